// Round 1
// baseline (1942.437 us; speedup 1.0000x reference)
//
#include <hip/hip_runtime.h>
#include <hip/hip_bf16.h>

#define NE 8
#define HID 2048
#define INTER 5120
#define NTOK 4096
#define OUT_HID (NTOK * HID)  // 8388608
#define BK 64

typedef short v8s __attribute__((ext_vector_type(8)));
typedef float v4f __attribute__((ext_vector_type(4)));

__device__ __forceinline__ unsigned short f2bf(float x) {
  unsigned u = __float_as_uint(x);
  u += 0x7FFFu + ((u >> 16) & 1u);  // round-to-nearest-even
  return (unsigned short)(u >> 16);
}

// LDS layout: rows of 64 bf16 (128B = 8 chunks of 16B), chunk c of row r stored
// at chunk position c ^ (r & 7)  -> conflict-free-ish ds_write_b128 staging and
// <=2-way ds_read_b128 fragment reads.
__device__ __forceinline__ int lds_byte(int r, int c) {
  return r * 128 + ((c ^ (r & 7)) << 4);
}

// ---------------- cast hidden_states fp32 -> bf16 ----------------
__global__ __launch_bounds__(256) void k_cast(const float* __restrict__ x,
                                              unsigned short* __restrict__ xb) {
  int i = (blockIdx.x * 256 + threadIdx.x) * 4;
  float4 f = *(const float4*)(x + i);
  ushort4 o;
  o.x = f2bf(f.x); o.y = f2bf(f.y); o.z = f2bf(f.z); o.w = f2bf(f.w);
  *(ushort4*)(xb + i) = o;
}

// ---------------- router: fp32 logits, top-2, softmax, expert lists ----------
__global__ __launch_bounds__(256) void k_router(const float* __restrict__ x,
                                                const float* __restrict__ gw,
                                                float* __restrict__ logits,
                                                int* __restrict__ counts,
                                                int* __restrict__ ltok,
                                                float* __restrict__ lwt) {
  int tok = blockIdx.x * 4 + (threadIdx.x >> 6);
  int lane = threadIdx.x & 63;
  const float* xr = x + (size_t)tok * HID;
  float acc[NE];
#pragma unroll
  for (int e = 0; e < NE; e++) acc[e] = 0.f;
  for (int h = lane; h < HID; h += 64) {
    float xv = xr[h];
    const float4* g = (const float4*)(gw + h * NE);
    float4 g0 = g[0], g1 = g[1];
    acc[0] += xv * g0.x; acc[1] += xv * g0.y;
    acc[2] += xv * g0.z; acc[3] += xv * g0.w;
    acc[4] += xv * g1.x; acc[5] += xv * g1.y;
    acc[6] += xv * g1.z; acc[7] += xv * g1.w;
  }
#pragma unroll
  for (int e = 0; e < NE; e++) {
#pragma unroll
    for (int off = 32; off > 0; off >>= 1)
      acc[e] += __shfl_down(acc[e], off, 64);
  }
  if (lane == 0) {
    int i0 = 0; float v0 = acc[0];
#pragma unroll
    for (int e = 1; e < NE; e++)
      if (acc[e] > v0) { v0 = acc[e]; i0 = e; }
    int i1 = -1; float v1 = -3.0e38f;
#pragma unroll
    for (int e = 0; e < NE; e++)
      if (e != i0 && acc[e] > v1) { v1 = acc[e]; i1 = e; }
    float e1 = __expf(v1 - v0);
    float inv = 1.f / (1.f + e1);
    int p0 = atomicAdd(&counts[i0], 1);
    ltok[i0 * NTOK + p0] = tok; lwt[i0 * NTOK + p0] = inv;
    int p1 = atomicAdd(&counts[i1], 1);
    ltok[i1 * NTOK + p1] = tok; lwt[i1 * NTOK + p1] = e1 * inv;
#pragma unroll
    for (int e = 0; e < NE; e++) logits[tok * NE + e] = acc[e];
  }
}

__global__ void k_prefix(const int* __restrict__ counts, int* __restrict__ bases) {
  if (threadIdx.x == 0 && blockIdx.x == 0) {
    int s = 0;
#pragma unroll
    for (int e = 0; e < NE; e++) { bases[e] = s; s += counts[e]; }
  }
}

// ---------------- pass1: gated = silu(x*w1) * (x*w3), per expert -------------
// tile: 128 tokens x 64 inter cols (both w1 and w3), BK=64, 4 waves (2x2)
__global__ __launch_bounds__(256) void k_pass1(
    const unsigned short* __restrict__ xb, const float* __restrict__ w1,
    const float* __restrict__ w3, const int* __restrict__ counts,
    const int* __restrict__ bases, const int* __restrict__ ltok,
    unsigned short* __restrict__ gated) {
  int e = blockIdx.z;
  int cnt = counts[e];
  int mt = blockIdx.y;
  if (mt * 128 >= cnt) return;
  int nt = blockIdx.x;
  int n0 = nt * 64;
  int base = bases[e];
  int tid = threadIdx.x;

  __shared__ unsigned short As[128 * BK];
  __shared__ unsigned short B1s[64 * BK];
  __shared__ unsigned short B3s[64 * BK];
  __shared__ int tokA[128];

  if (tid < 128) {
    int idx = mt * 128 + tid;
    tokA[tid] = (idx < cnt) ? ltok[e * NTOK + idx] : ltok[e * NTOK];
  }
  __syncthreads();

  const float* W1e = w1 + (size_t)e * HID * INTER;
  const float* W3e = w3 + (size_t)e * HID * INTER;
  int lane = tid & 63, wave = tid >> 6;
  int wm = wave >> 1, wn = wave & 1;

  const v4f vzero = {0.f, 0.f, 0.f, 0.f};
  v4f acc1[4][2], acc3[4][2];
#pragma unroll
  for (int i = 0; i < 4; i++)
#pragma unroll
    for (int j = 0; j < 2; j++) { acc1[i][j] = vzero; acc3[i][j] = vzero; }

  const float* WB = (tid < 128) ? W1e : W3e;
  unsigned short* Bst = (tid < 128) ? B1s : B3s;
  int tb = tid & 127;
  int q = lane >> 4, li = lane & 15;

  for (int k0 = 0; k0 < HID; k0 += BK) {
    // stage A: 128 rows x 64 k, gathered token rows (pre-cast bf16)
#pragma unroll
    for (int j = 0; j < 4; j++) {
      int s = j * 256 + tid;
      int r = s >> 3, c = s & 7;
      v8s v = *(const v8s*)(xb + (size_t)tokA[r] * HID + k0 + c * 8);
      *(v8s*)((char*)As + lds_byte(r, c)) = v;
    }
    // stage B (transpose + cast): tid<128 -> w1, else w3
#pragma unroll
    for (int jj = 0; jj < 2; jj++) {
      int s = jj * 128 + tb;        // 256 pair-slots per matrix
      int np = s & 31, c = s >> 5;  // n-pair, k-chunk
      int n = np * 2;
      const float* src = WB + (size_t)(k0 + c * 8) * INTER + n0 + n;
      v8s vc0, vc1;
#pragma unroll
      for (int i = 0; i < 8; i++) {
        float2 f = *(const float2*)(src + (size_t)i * INTER);
        vc0[i] = (short)f2bf(f.x);
        vc1[i] = (short)f2bf(f.y);
      }
      *(v8s*)((char*)Bst + lds_byte(n, c)) = vc0;
      *(v8s*)((char*)Bst + lds_byte(n + 1, c)) = vc1;
    }
    __syncthreads();
#pragma unroll
    for (int h = 0; h < 2; h++) {
      int ch = h * 4 + q;
      v8s a[4], b1f[2], b3f[2];
#pragma unroll
      for (int mi = 0; mi < 4; mi++) {
        int r = wm * 64 + mi * 16 + li;
        a[mi] = *(const v8s*)((char*)As + lds_byte(r, ch));
      }
#pragma unroll
      for (int ni = 0; ni < 2; ni++) {
        int n = wn * 32 + ni * 16 + li;
        b1f[ni] = *(const v8s*)((char*)B1s + lds_byte(n, ch));
        b3f[ni] = *(const v8s*)((char*)B3s + lds_byte(n, ch));
      }
#pragma unroll
      for (int mi = 0; mi < 4; mi++)
#pragma unroll
        for (int ni = 0; ni < 2; ni++) {
          acc1[mi][ni] = __builtin_amdgcn_mfma_f32_16x16x32_bf16(a[mi], b1f[ni], acc1[mi][ni], 0, 0, 0);
          acc3[mi][ni] = __builtin_amdgcn_mfma_f32_16x16x32_bf16(a[mi], b3f[ni], acc3[mi][ni], 0, 0, 0);
        }
    }
    __syncthreads();
  }
  // epilogue: silu(a1)*a3 -> gated[slot][inter]
#pragma unroll
  for (int mi = 0; mi < 4; mi++) {
#pragma unroll
    for (int reg = 0; reg < 4; reg++) {
      int m = mt * 128 + wm * 64 + mi * 16 + q * 4 + reg;
      if (m < cnt) {
        size_t row = (size_t)(base + m) * INTER;
#pragma unroll
        for (int ni = 0; ni < 2; ni++) {
          int n = n0 + wn * 32 + ni * 16 + li;
          float x1 = acc1[mi][ni][reg];
          float x3 = acc3[mi][ni][reg];
          float g = x1 / (1.f + __expf(-x1)) * x3;
          gated[row + n] = f2bf(g);
        }
      }
    }
  }
}

// ---------------- pass2: out += w_tok * (gated * w2) -------------------------
// tile: 128 slots x 128 hid cols, BK=64, 4 waves (2x2)
__global__ __launch_bounds__(256) void k_pass2(
    const unsigned short* __restrict__ gated, const float* __restrict__ w2,
    const int* __restrict__ counts, const int* __restrict__ bases,
    const int* __restrict__ ltok, const float* __restrict__ lwt,
    float* __restrict__ out) {
  int e = blockIdx.z;
  int cnt = counts[e];
  int mt = blockIdx.y;
  if (mt * 128 >= cnt) return;
  int nt = blockIdx.x;
  int n0 = nt * 128;
  int base = bases[e];
  int tid = threadIdx.x;

  __shared__ unsigned short As[128 * BK];
  __shared__ unsigned short Bs2[128 * BK];
  __shared__ int tokL[128];
  __shared__ float wL[128];

  if (tid < 128) {
    int idx = mt * 128 + tid;
    bool v = idx < cnt;
    tokL[tid] = v ? ltok[e * NTOK + idx] : 0;
    wL[tid] = v ? lwt[e * NTOK + idx] : 0.f;
  }
  __syncthreads();

  const float* W2e = w2 + (size_t)e * INTER * HID;
  int lane = tid & 63, wave = tid >> 6;
  int wm = wave >> 1, wn = wave & 1;
  int q = lane >> 4, li = lane & 15;

  const v4f vzero = {0.f, 0.f, 0.f, 0.f};
  v4f acc[4][4];
#pragma unroll
  for (int i = 0; i < 4; i++)
#pragma unroll
    for (int j = 0; j < 4; j++) acc[i][j] = vzero;

  for (int k0 = 0; k0 < INTER; k0 += BK) {
    // stage A from gated (contiguous slots)
#pragma unroll
    for (int j = 0; j < 4; j++) {
      int s = j * 256 + tid;
      int r = s >> 3, c = s & 7;
      int idx = mt * 128 + r;
      if (idx >= cnt) idx = 0;
      v8s v = *(const v8s*)(gated + (size_t)(base + idx) * INTER + k0 + c * 8);
      *(v8s*)((char*)As + lds_byte(r, c)) = v;
    }
    // stage B (transpose + cast w2)
#pragma unroll
    for (int jj = 0; jj < 2; jj++) {
      int s = jj * 256 + tid;       // 512 pair-slots
      int np = s & 63, c = s >> 6;  // n-pair, k-chunk
      int n = np * 2;
      const float* src = W2e + (size_t)(k0 + c * 8) * HID + n0 + n;
      v8s vc0, vc1;
#pragma unroll
      for (int i = 0; i < 8; i++) {
        float2 f = *(const float2*)(src + (size_t)i * HID);
        vc0[i] = (short)f2bf(f.x);
        vc1[i] = (short)f2bf(f.y);
      }
      *(v8s*)((char*)Bs2 + lds_byte(n, c)) = vc0;
      *(v8s*)((char*)Bs2 + lds_byte(n + 1, c)) = vc1;
    }
    __syncthreads();
#pragma unroll
    for (int h = 0; h < 2; h++) {
      int ch = h * 4 + q;
      v8s a[4], b[4];
#pragma unroll
      for (int mi = 0; mi < 4; mi++) {
        int r = wm * 64 + mi * 16 + li;
        a[mi] = *(const v8s*)((char*)As + lds_byte(r, ch));
      }
#pragma unroll
      for (int ni = 0; ni < 4; ni++) {
        int n = wn * 64 + ni * 16 + li;
        b[ni] = *(const v8s*)((char*)Bs2 + lds_byte(n, ch));
      }
#pragma unroll
      for (int mi = 0; mi < 4; mi++)
#pragma unroll
        for (int ni = 0; ni < 4; ni++)
          acc[mi][ni] = __builtin_amdgcn_mfma_f32_16x16x32_bf16(a[mi], b[ni], acc[mi][ni], 0, 0, 0);
    }
    __syncthreads();
  }
  // epilogue: weighted atomic accumulate into out (zero-initialized)
#pragma unroll
  for (int mi = 0; mi < 4; mi++) {
#pragma unroll
    for (int reg = 0; reg < 4; reg++) {
      int ml = wm * 64 + mi * 16 + q * 4 + reg;
      int tok = tokL[ml];
      float w = wL[ml];
      float* orow = out + (size_t)tok * HID;
#pragma unroll
      for (int ni = 0; ni < 4; ni++) {
        int n = n0 + wn * 64 + ni * 16 + li;
        atomicAdd(orow + n, w * acc[mi][ni][reg]);
      }
    }
  }
}

extern "C" void kernel_launch(void* const* d_in, const int* in_sizes, int n_in,
                              void* d_out, int out_size, void* d_ws, size_t ws_size,
                              hipStream_t stream) {
  const float* x = (const float*)d_in[0];
  const float* gw = (const float*)d_in[1];
  const float* w1 = (const float*)d_in[2];
  const float* w3 = (const float*)d_in[3];
  const float* w2 = (const float*)d_in[4];
  float* out = (float*)d_out;
  float* logits = out + OUT_HID;

  char* ws = (char*)d_ws;
  size_t off = 0;
  unsigned short* xb = (unsigned short*)(ws + off);
  off += (size_t)NTOK * HID * 2;                    // 16.8 MB
  unsigned short* gated = (unsigned short*)(ws + off);
  off += (size_t)NTOK * 2 * INTER * 2;              // 83.9 MB
  int* counts = (int*)(ws + off); off += 256;
  int* bases = (int*)(ws + off);  off += 256;
  int* ltok = (int*)(ws + off);   off += (size_t)NE * NTOK * 4;
  float* lwt = (float*)(ws + off); off += (size_t)NE * NTOK * 4;
  if (ws_size < off) return;  // workspace too small — fail loudly (zero output)

  hipMemsetAsync(d_out, 0, (size_t)out_size * sizeof(float), stream);
  hipMemsetAsync(counts, 0, NE * sizeof(int), stream);

  k_cast<<<(NTOK * HID) / 1024, 256, 0, stream>>>(x, xb);
  k_router<<<NTOK / 4, 256, 0, stream>>>(x, gw, logits, counts, ltok, lwt);
  k_prefix<<<1, 64, 0, stream>>>(counts, bases);
  k_pass1<<<dim3(INTER / 64, NTOK / 128, NE), 256, 0, stream>>>(
      xb, w1, w3, counts, bases, ltok, gated);
  k_pass2<<<dim3(HID / 128, NTOK / 128, NE), 256, 0, stream>>>(
      gated, w2, counts, bases, ltok, lwt, out);
}